// Round 10
// baseline (277.467 us; speedup 1.0000x reference)
//
#include <hip/hip_runtime.h>
#include <math.h>

#define B_  2
#define S_  2048
#define D_  1024
#define H_  16
#define HD_ 64
#define M_  (B_*S_)

typedef unsigned short ushort_t;
typedef unsigned int   uint_t;
typedef __attribute__((ext_vector_type(8))) short bf16x8;
typedef __attribute__((ext_vector_type(4))) float f32x4;

__device__ __forceinline__ ushort_t f2bf(float f) {
    uint_t u = __builtin_bit_cast(uint_t, f);
    u += 0x7FFFu + ((u >> 16) & 1u);           // RNE
    return (ushort_t)(u >> 16);
}
__device__ __forceinline__ float bf2f(ushort_t h) {
    uint_t u = (uint_t)h << 16;
    return __builtin_bit_cast(float, u);
}
// truncating pack: two f32 -> (bf16(lo) | bf16(hi)<<16), one v_perm_b32
__device__ __forceinline__ uint_t pkt(float lo, float hi) {
    return __builtin_amdgcn_perm(__builtin_bit_cast(uint_t, hi),
                                 __builtin_bit_cast(uint_t, lo), 0x07060302u);
}
// async global->LDS, 16B per lane; lds addr = wave-uniform base + lane*16
__device__ __forceinline__ void dma16(const ushort_t* g, ushort_t* l) {
    __builtin_amdgcn_global_load_lds(
        (const __attribute__((address_space(1))) uint_t*)g,
        (__attribute__((address_space(3))) uint_t*)l, 16, 0, 0);
}
// swizzled fragment read from unpadded [row][64] bf16 LDS tile
__device__ __forceinline__ bf16x8 fragr(const ushort_t* base, int row, int chunk) {
    return *(const bf16x8*)&base[row * 64 + (((chunk ^ (row & 7)) << 3))];
}

// ---------------------------------------------------------------------------
// prep: (a) 3 weight transposes f32->bf16  (b) q f32->bf16  (c) K->Kb bf16,
// V->VT bf16 * gamma^{-ml}, per-chunk G^T (bf16) for the state recurrence.
// Flattened grid: [0,3072) transp | [3072,7168) q cvt | [7168,8192) kv+G.
// ---------------------------------------------------------------------------
__global__ __launch_bounds__(256)
void prep(const float* __restrict__ W0, const float* __restrict__ W1,
          const float* __restrict__ W2, ushort_t* __restrict__ T0,
          ushort_t* __restrict__ T1, ushort_t* __restrict__ T2,
          const float* __restrict__ q, ushort_t* __restrict__ q_bf,
          const float* __restrict__ K, const float* __restrict__ V,
          const float* __restrict__ gammas, ushort_t* __restrict__ Kb,
          ushort_t* __restrict__ VT, ushort_t* __restrict__ Gg) {
    __shared__ ushort_t sh[9216];   // 18 KB, reused per branch
    const int bi = blockIdx.x;
    const int tid = threadIdx.x;

    if (bi < 3072) {                // ---- weight transpose+convert
        float* T = (float*)sh;      // [32][36]
        const int z = bi >> 10, rem = bi & 1023;
        const int kt = rem & 31, nt = rem >> 5;
        const float*  W  = (z == 0) ? W0 : (z == 1) ? W1 : W2;
        ushort_t*     WT = (z == 0) ? T0 : (z == 1) ? T1 : T2;
        const int rr = tid >> 3, cc = (tid & 7) * 4;
        float4 w4 = *(const float4*)(W + (size_t)(kt * 32 + rr) * D_ + nt * 32 + cc);
        T[rr * 36 + cc + 0] = w4.x; T[rr * 36 + cc + 1] = w4.y;
        T[rr * 36 + cc + 2] = w4.z; T[rr * 36 + cc + 3] = w4.w;
        __syncthreads();
        ushort_t o[4];
        #pragma unroll
        for (int j = 0; j < 4; ++j) o[j] = f2bf(T[(cc + j) * 36 + rr]);
        *(ushort4*)(WT + (size_t)(nt * 32 + rr) * D_ + kt * 32 + cc) =
            make_ushort4(o[0], o[1], o[2], o[3]);
        return;
    }
    if (bi < 7168) {                // ---- q convert
        const int i = ((bi - 3072) * 256 + tid) * 4;
        float4 x = *(const float4*)(q + i);
        *(ushort4*)(q_bf + i) = make_ushort4(f2bf(x.x), f2bf(x.y), f2bf(x.z), f2bf(x.w));
        return;
    }
    // ---- K/V convert + chunk outer product G^T
    ushort_t* Tv = sh;              // [val][ml] stride 72
    ushort_t* Tk = sh + 4608;       // [kappa][ml] stride 72
    const int rem = bi - 7168;
    const int mt = rem & 31, h = (rem >> 5) & 15, b = rem >> 9;
    const int m0 = mt * 64;
    const int r = tid >> 2, c0 = (tid & 3) * 16;
    const float lg = log2f(gammas[h]);
    const float gm = exp2f(-(float)r * lg);
    {
        const float* src = K + ((size_t)(b * S_ + m0 + r)) * D_ + h * HD_ + c0;
        ushort_t kb[16];
        #pragma unroll
        for (int j4 = 0; j4 < 4; ++j4) {
            float4 x = *(const float4*)(src + j4 * 4);
            kb[j4 * 4 + 0] = f2bf(x.x); kb[j4 * 4 + 1] = f2bf(x.y);
            kb[j4 * 4 + 2] = f2bf(x.z); kb[j4 * 4 + 3] = f2bf(x.w);
        }
        ushort_t* dst = Kb + ((size_t)(b * S_ + m0 + r)) * D_ + h * HD_ + c0;
        *(uint4*)(dst + 0) = *(const uint4*)&kb[0];
        *(uint4*)(dst + 8) = *(const uint4*)&kb[8];
        #pragma unroll
        for (int j = 0; j < 16; ++j) Tk[(c0 + j) * 72 + r] = kb[j];
    }
    {
        const float* src = V + ((size_t)(b * S_ + m0 + r)) * D_ + h * HD_ + c0;
        #pragma unroll
        for (int j4 = 0; j4 < 4; ++j4) {
            float4 x = *(const float4*)(src + j4 * 4);
            Tv[(c0 + j4 * 4 + 0) * 72 + r] = f2bf(x.x * gm);
            Tv[(c0 + j4 * 4 + 1) * 72 + r] = f2bf(x.y * gm);
            Tv[(c0 + j4 * 4 + 2) * 72 + r] = f2bf(x.z * gm);
            Tv[(c0 + j4 * 4 + 3) * 72 + r] = f2bf(x.w * gm);
        }
    }
    __syncthreads();
    {
        ushort_t* dst = VT + ((size_t)((b * H_ + h) * HD_ + r)) * S_ + m0 + c0;
        *(uint4*)(dst + 0) = *(const uint4*)&Tv[r * 72 + c0 + 0];
        *(uint4*)(dst + 8) = *(const uint4*)&Tv[r * 72 + c0 + 8];
    }
    const int w = tid >> 6, lane = tid & 63, quad = lane >> 4, l15 = lane & 15;
    bf16x8 af0 = *(const bf16x8*)&Tv[(w * 16 + l15) * 72 + quad * 8];
    bf16x8 af1 = *(const bf16x8*)&Tv[(w * 16 + l15) * 72 + 32 + quad * 8];
    ushort_t* gout = Gg + ((size_t)((b * H_ + h) * 32 + mt)) * 4096;
    #pragma unroll
    for (int kt2 = 0; kt2 < 4; ++kt2) {
        bf16x8 bf0 = *(const bf16x8*)&Tk[(kt2 * 16 + l15) * 72 + quad * 8];
        bf16x8 bf1 = *(const bf16x8*)&Tk[(kt2 * 16 + l15) * 72 + 32 + quad * 8];
        f32x4 g = {};
        g = __builtin_amdgcn_mfma_f32_16x16x32_bf16(af0, bf0, g, 0, 0, 0);
        g = __builtin_amdgcn_mfma_f32_16x16x32_bf16(af1, bf1, g, 0, 0, 0);
        #pragma unroll
        for (int reg = 0; reg < 4; ++reg)
            gout[(w * 16 + quad * 4 + reg) * 64 + kt2 * 16 + l15] = f2bf(g[reg]);
    }
}

// ---------------------------------------------------------------------------
// Fused dual GEMM + chunk-scan epilogue. MFMA fragments loaded DIRECTLY from
// global (wave = 16 rows x 64B cache lines, fully coalesced): no LDS staging,
// no barriers in the K-loop. LDS only for the 32 KB scan epilogue.
// ---------------------------------------------------------------------------
__global__ __launch_bounds__(256)
void gemm_dual_scan(const ushort_t* __restrict__ A, const ushort_t* __restrict__ BTi,
                    const ushort_t* __restrict__ BTg, const float* __restrict__ bi,
                    const float* __restrict__ bg, uint_t* __restrict__ PH,
                    float* __restrict__ cA, float* __restrict__ cU) {
    __shared__ ushort_t Us[8192];   // [128][64] bf16 u
    __shared__ ushort_t Gu[8192];   // [128][64] u16 gate
    const int tid = threadIdx.x;
    const int n0 = blockIdx.x * 64, m0 = blockIdx.y * 128;
    const int w = tid >> 6, lane = tid & 63, quad = lane >> 4, l15 = lane & 15;
    const int wr = (w >> 1) * 64, wc = (w & 1) * 32;

    f32x4 acc_i[4][2] = {};
    f32x4 acc_g[4][2] = {};

    const ushort_t* ap[4];
    const ushort_t* bip[2];
    const ushort_t* bgp[2];
    #pragma unroll
    for (int i = 0; i < 4; ++i)
        ap[i] = A + (size_t)(m0 + wr + 16 * i + l15) * D_ + quad * 8;
    #pragma unroll
    for (int j = 0; j < 2; ++j) {
        bip[j] = BTi + (size_t)(n0 + wc + 16 * j + l15) * D_ + quad * 8;
        bgp[j] = BTg + (size_t)(n0 + wc + 16 * j + l15) * D_ + quad * 8;
    }

    #pragma unroll 2
    for (int k0 = 0; k0 < D_; k0 += 32) {
        bf16x8 af[4], bfi[2], bfg[2];
        #pragma unroll
        for (int i = 0; i < 4; ++i) af[i] = *(const bf16x8*)(ap[i] + k0);
        #pragma unroll
        for (int j = 0; j < 2; ++j) {
            bfi[j] = *(const bf16x8*)(bip[j] + k0);
            bfg[j] = *(const bf16x8*)(bgp[j] + k0);
        }
        #pragma unroll
        for (int i = 0; i < 4; ++i)
            #pragma unroll
            for (int j = 0; j < 2; ++j) {
                acc_i[i][j] = __builtin_amdgcn_mfma_f32_16x16x32_bf16(
                    af[i], bfi[j], acc_i[i][j], 0, 0, 0);
                acc_g[i][j] = __builtin_amdgcn_mfma_f32_16x16x32_bf16(
                    af[i], bfg[j], acc_g[i][j], 0, 0, 0);
            }
    }

    #pragma unroll
    for (int j = 0; j < 2; ++j) {
        const int n = wc + 16 * j + l15;
        const float bbi = bi[n0 + n], bbg = bg[n0 + n];
        #pragma unroll
        for (int i = 0; i < 4; ++i) {
            #pragma unroll
            for (int r = 0; r < 4; ++r) {
                const int m = wr + 16 * i + quad * 4 + r;
                Us[m * 64 + n] = f2bf(acc_i[i][j][r] + bbi);
                float g = 1.0f / (1.0f + __expf(-(acc_g[i][j][r] + bbg)));
                Gu[m * 64 + n] = (ushort_t)__float2uint_rn(g * 65535.0f);
            }
        }
    }
    __syncthreads();

    // per-thread serial scan over one 32-chunk of one channel
    const int nl = tid & 63, c = tid >> 6;
    const int gmb = m0 + c * 32;
    const size_t gbase = (size_t)gmb * D_ + n0 + nl;
    float Aa = 1.0f, hh = 0.0f;
    #pragma unroll 4
    for (int j = 0; j < 32; ++j) {
        const float g = (float)Gu[(c * 32 + j) * 64 + nl] * (1.0f / 65535.0f);
        const float u = bf2f(Us[(c * 32 + j) * 64 + nl]);
        Aa *= g;
        hh = fmaf(g, hh, u);
        PH[gbase + (size_t)j * D_] = pkt(Aa, hh);
    }
    const int bb = gmb >> 11;
    const int ch = (gmb & 2047) >> 5;
    const int ci = ((bb * 64 + ch) << 10) + n0 + nl;
    cA[ci] = Aa;
    cU[ci] = hh;
}

// ---------------------------------------------------------------------------
// Merged mid-kernels: blocks [0,128) = state scan (S_c = g64*(S_{c-1}+G));
// blocks [128,136) = chunk-level gated scan producing carry-ins.
// ---------------------------------------------------------------------------
__global__ __launch_bounds__(256)
void mid_scan(const ushort_t* __restrict__ Gg, const float* __restrict__ gammas,
              ushort_t* __restrict__ Sb, const float* __restrict__ cA,
              const float* __restrict__ cU, float* __restrict__ cIn) {
    const int bi = blockIdx.x;
    if (bi < 128) {
        const int sl = bi & 3, h = (bi >> 2) & 15, b = bi >> 6;
        const float g64 = exp2f(64.0f * log2f(gammas[h]));
        const int r = threadIdx.x >> 4;
        const int cb = (threadIdx.x & 15) * 4;
        const size_t base = ((size_t)((b * H_ + h) * 32)) * 4096 + (sl * 16 + r) * 64 + cb;
        float4 S = make_float4(0.f, 0.f, 0.f, 0.f);
        for (int c = 0; c < 32; ++c) {
            ushort4 g4 = *(const ushort4*)(Gg + base + (size_t)c * 4096);
            ushort4 sb;
            sb.x = f2bf(S.x); sb.y = f2bf(S.y); sb.z = f2bf(S.z); sb.w = f2bf(S.w);
            *(ushort4*)(Sb + base + (size_t)c * 4096) = sb;
            S.x = g64 * (S.x + bf2f(g4.x)); S.y = g64 * (S.y + bf2f(g4.y));
            S.z = g64 * (S.z + bf2f(g4.z)); S.w = g64 * (S.w + bf2f(g4.w));
        }
        return;
    }
    const int t = (bi - 128) * 256 + threadIdx.x;   // 0..2047
    const int d = t & 1023, b = t >> 10;
    float h = 0.0f;
    for (int c0 = 0; c0 < 64; c0 += 16) {
        float Av[16], Uv[16];
        #pragma unroll
        for (int j = 0; j < 16; ++j) {
            const int idx = ((b * 64 + c0 + j) << 10) + d;
            Av[j] = cA[idx]; Uv[j] = cU[idx];
        }
        #pragma unroll
        for (int j = 0; j < 16; ++j) {
            cIn[((b * 64 + c0 + j) << 10) + d] = h;
            h = fmaf(Av[j], h, Uv[j]);
        }
    }
}

// h = Hloc + cIn[chunk] * Pp  -> bf16
__global__ __launch_bounds__(256)
void scan_fix(const uint_t* __restrict__ PH, const float* __restrict__ cIn,
              ushort_t* __restrict__ hout) {
    const int i = (blockIdx.x * 256 + threadIdx.x) * 4;
    const int m = i >> 10, d = i & 1023;
    const int b = m >> 11, ch = (m & 2047) >> 5;
    uint4 p = *(const uint4*)(PH + i);
    float4 ci = *(const float4*)(cIn + ((b * 64 + ch) << 10) + d);
    ushort4 o;
    o.x = f2bf(fmaf(ci.x, bf2f((ushort_t)(p.x & 0xFFFF)), bf2f((ushort_t)(p.x >> 16))));
    o.y = f2bf(fmaf(ci.y, bf2f((ushort_t)(p.y & 0xFFFF)), bf2f((ushort_t)(p.y >> 16))));
    o.z = f2bf(fmaf(ci.z, bf2f((ushort_t)(p.z & 0xFFFF)), bf2f((ushort_t)(p.z >> 16))));
    o.w = f2bf(fmaf(ci.w, bf2f((ushort_t)(p.w & 0xFFFF)), bf2f((ushort_t)(p.w >> 16))));
    *(ushort4*)(hout + i) = o;
}

// ---------------------------------------------------------------------------
// Retention with fused W_out GEMM (direct-from-global fragments, no staging
// barriers). K/V/S DMAs issued up front drain under the GEMM. Then chunkwise
// retention: out^T = S^T.q + VT.(masked QK^T), epilogue scale gamma^{nl}.
// LDS 40 KB -> 4 blocks/CU.
// ---------------------------------------------------------------------------
__global__ __launch_bounds__(256)
void retention_fused(const ushort_t* __restrict__ Hb, const ushort_t* __restrict__ WTo,
                     const float* __restrict__ bo, const ushort_t* __restrict__ Kb,
                     const ushort_t* __restrict__ VT, const ushort_t* __restrict__ Sb,
                     const float* __restrict__ gammas, float* __restrict__ Out) {
    __shared__ ushort_t smem[20480];   // 40 KB (ushort units)
    ushort_t* Qs = smem;               // [nl][64] swizzled
    ushort_t* Ps = smem + 4096;        // [nl][ml] swizzled
    ushort_t* Ks = smem + 8192;        // [ml][64]
    ushort_t* Vt = smem + 12288;       // [val][ml]
    ushort_t* Ss = smem + 16384;       // [val][kappa]
    const int tid = threadIdx.x;
    const int nt = blockIdx.x, h = blockIdx.y, b = blockIdx.z;
    const int n0 = nt * 64;
    const float lg = log2f(gammas[h]);
    const int w = tid >> 6, lane = tid & 63, quad = lane >> 4, l15 = lane & 15;
    const int l8 = lane & 7, lr8 = lane >> 3;
    const int nl = w * 16 + l15;
    const size_t bS = (size_t)b * S_;
    const size_t vrow0 = (size_t)((b * H_ + h) * HD_);
    const size_t sbase = ((size_t)((b * H_ + h) * 32 + nt)) * 4096;

    // K/V/S DMAs: complete during the GEMM below (latency hidden)
    #pragma unroll
    for (int t = 0; t < 2; ++t) {
        const int row = w * 16 + t * 8 + lr8;
        const int gc = ((l8 ^ (row & 7)) << 3);
        dma16(Kb + (bS + n0 + row) * D_ + h * HD_ + gc, &Ks[row * 64 + l8 * 8]);
        dma16(VT + (vrow0 + row) * S_ + n0 + gc,        &Vt[row * 64 + l8 * 8]);
        dma16(Sb + sbase + (size_t)row * 64 + gc,       &Ss[row * 64 + l8 * 8]);
    }

    // qp tile GEMM: direct global fragments, no barriers
    const ushort_t* hp = Hb + (bS + n0 + w * 16 + l15) * D_ + quad * 8;
    const ushort_t* wp[4];
    #pragma unroll
    for (int ct = 0; ct < 4; ++ct)
        wp[ct] = WTo + ((size_t)(h * 64 + ct * 16 + l15)) * D_ + quad * 8;

    f32x4 acc[4] = {};
    #pragma unroll 2
    for (int k0 = 0; k0 < D_; k0 += 32) {
        bf16x8 af = *(const bf16x8*)(hp + k0);
        #pragma unroll
        for (int ct = 0; ct < 4; ++ct) {
            bf16x8 bf = *(const bf16x8*)(wp[ct] + k0);
            acc[ct] = __builtin_amdgcn_mfma_f32_16x16x32_bf16(af, bf, acc[ct], 0, 0, 0);
        }
    }

    // qp -> Qs (swizzled bf16)
    #pragma unroll
    for (int ct = 0; ct < 4; ++ct) {
        const int n = ct * 16 + l15;
        const float bb = bo[h * 64 + n];
        #pragma unroll
        for (int r = 0; r < 4; ++r) {
            const int m = w * 16 + quad * 4 + r;
            Qs[m * 64 + (((n >> 3) ^ (m & 7)) << 3) + (n & 7)] =
                f2bf((acc[ct][r] + bb) * 0.125f);
        }
    }
    __syncthreads();   // drains K/V/S DMAs + publishes Qs

    bf16x8 qf0 = fragr(Qs, nl, quad);
    bf16x8 qf1 = fragr(Qs, nl, 4 + quad);

    f32x4 o[4] = {};
    // cross-chunk: o += S^T-rows x Q
    #pragma unroll
    for (int ct = 0; ct < 4; ++ct) {
        bf16x8 sf0 = fragr(Ss, ct * 16 + l15, quad);
        bf16x8 sf1 = fragr(Ss, ct * 16 + l15, 4 + quad);
        o[ct] = __builtin_amdgcn_mfma_f32_16x16x32_bf16(sf0, qf0, o[ct], 0, 0, 0);
        o[ct] = __builtin_amdgcn_mfma_f32_16x16x32_bf16(sf1, qf1, o[ct], 0, 0, 0);
    }
    // intra-chunk scores^T, causal mask, pack -> Ps
    #pragma unroll
    for (int mt2 = 0; mt2 < 4; ++mt2) {
        bf16x8 kf0 = fragr(Ks, mt2 * 16 + l15, quad);
        bf16x8 kf1 = fragr(Ks, mt2 * 16 + l15, 4 + quad);
        f32x4 s = {};
        s = __builtin_amdgcn_mfma_f32_16x16x32_bf16(kf0, qf0, s, 0, 0, 0);
        s = __builtin_amdgcn_mfma_f32_16x16x32_bf16(kf1, qf1, s, 0, 0, 0);
        const int mbase = mt2 * 16 + quad * 4;
        #pragma unroll
        for (int r = 0; r < 4; ++r)
            if (nl < mbase + r) s[r] = 0.0f;
        uint2 pw; pw.x = pkt(s[0], s[1]); pw.y = pkt(s[2], s[3]);
        const int chunk = mbase >> 3;
        *(uint2*)&Ps[nl * 64 + ((chunk ^ (nl & 7)) << 3) + (mbase & 7)] = pw;
    }
    // PV: o += Vt-rows x Ps-row-nl  (Ps rows wave-private)
    bf16x8 pf0 = fragr(Ps, nl, quad);
    bf16x8 pf1 = fragr(Ps, nl, 4 + quad);
    #pragma unroll
    for (int ct = 0; ct < 4; ++ct) {
        bf16x8 vf0 = fragr(Vt, ct * 16 + l15, quad);
        bf16x8 vf1 = fragr(Vt, ct * 16 + l15, 4 + quad);
        o[ct] = __builtin_amdgcn_mfma_f32_16x16x32_bf16(vf0, pf0, o[ct], 0, 0, 0);
        o[ct] = __builtin_amdgcn_mfma_f32_16x16x32_bf16(vf1, pf1, o[ct], 0, 0, 0);
    }

    const float esc = exp2f((float)nl * lg);
    const size_t ob = (bS + n0 + nl) * D_ + h * HD_;
    #pragma unroll
    for (int ct = 0; ct < 4; ++ct) {
        f32x4 t = o[ct] * esc;
        *(f32x4*)(Out + ob + ct * 16 + quad * 4) = t;
    }
}

// ---------------------------------------------------------------------------
extern "C" void kernel_launch(void* const* d_in, const int* in_sizes, int n_in,
                              void* d_out, int out_size, void* d_ws, size_t ws_size,
                              hipStream_t stream) {
    const float* q      = (const float*)d_in[0];
    const float* k      = (const float*)d_in[1];
    const float* v      = (const float*)d_in[2];
    const float* W_in   = (const float*)d_in[3];
    const float* b_in   = (const float*)d_in[4];
    const float* W_gate = (const float*)d_in[5];
    const float* b_gate = (const float*)d_in[6];
    const float* W_out  = (const float*)d_in[7];
    const float* b_out  = (const float*)d_in[8];
    const float* gammas = (const float*)d_in[9];
    float* out = (float*)d_out;

    char* ws = (char*)d_ws;
    const size_t MB = 1024 * 1024;
    ushort_t* q_bf    = (ushort_t*)(ws);              // [0,8)
    ushort_t* k_bf    = (ushort_t*)(ws + 8 * MB);     // [8,16)
    ushort_t* VT      = (ushort_t*)(ws + 16 * MB);    // [16,24)
    ushort_t* WT_in   = (ushort_t*)(ws + 24 * MB);    // [24,26)
    ushort_t* WT_gate = (ushort_t*)(ws + 26 * MB);    // [26,28)
    ushort_t* WT_out  = (ushort_t*)(ws + 28 * MB);    // [28,30)
    ushort_t* Sb      = (ushort_t*)(ws + 30 * MB);    // [30,38)
    ushort_t* Gg      = (ushort_t*)(ws + 38 * MB);    // [38,46)
    uint_t*   PH      = (uint_t*)(ws + 48 * MB);      // [48,64)
    ushort_t* h_bf    = (ushort_t*)(ws + 64 * MB);    // [64,72)
    float*    cA      = (float*)(ws + 72 * MB);
    float*    cU      = (float*)(ws + 72 * MB + 512 * 1024);
    float*    cIn     = (float*)(ws + 73 * MB);

    prep<<<8192, 256, 0, stream>>>(W_in, W_gate, W_out, WT_in, WT_gate, WT_out,
                                   q, q_bf, k, v, gammas, k_bf, VT, Gg);

    gemm_dual_scan<<<dim3(D_ / 64, M_ / 128), 256, 0, stream>>>(
        q_bf, WT_in, WT_gate, b_in, b_gate, PH, cA, cU);

    mid_scan<<<136, 256, 0, stream>>>(Gg, gammas, Sb, cA, cU, cIn);

    scan_fix<<<(M_ * D_) / 1024, 256, 0, stream>>>(PH, cIn, h_bf);

    retention_fused<<<dim3(S_ / 64, H_, B_), 256, 0, stream>>>(
        h_bf, WT_out, b_out, k_bf, VT, Sb, gammas, out);
}

// Round 11
// 201.705 us; speedup vs baseline: 1.3756x; 1.3756x over previous
//
#include <hip/hip_runtime.h>
#include <math.h>

#define B_  2
#define S_  2048
#define D_  1024
#define H_  16
#define HD_ 64
#define M_  (B_*S_)

typedef unsigned short ushort_t;
typedef unsigned int   uint_t;
typedef __attribute__((ext_vector_type(8))) short bf16x8;
typedef __attribute__((ext_vector_type(4))) float f32x4;

__device__ __forceinline__ ushort_t f2bf(float f) {
    uint_t u = __builtin_bit_cast(uint_t, f);
    u += 0x7FFFu + ((u >> 16) & 1u);           // RNE
    return (ushort_t)(u >> 16);
}
__device__ __forceinline__ float bf2f(ushort_t h) {
    uint_t u = (uint_t)h << 16;
    return __builtin_bit_cast(float, u);
}
// truncating pack: two f32 -> (bf16(lo) | bf16(hi)<<16), one v_perm_b32
__device__ __forceinline__ uint_t pkt(float lo, float hi) {
    return __builtin_amdgcn_perm(__builtin_bit_cast(uint_t, hi),
                                 __builtin_bit_cast(uint_t, lo), 0x07060302u);
}
// async global->LDS, 16B per lane; lds addr = wave-uniform base + lane*16
__device__ __forceinline__ void dma16(const ushort_t* g, ushort_t* l) {
    __builtin_amdgcn_global_load_lds(
        (const __attribute__((address_space(1))) uint_t*)g,
        (__attribute__((address_space(3))) uint_t*)l, 16, 0, 0);
}
// swizzled fragment read from unpadded [row][64] bf16 LDS tile
__device__ __forceinline__ bf16x8 fragr(const ushort_t* base, int row, int chunk) {
    return *(const bf16x8*)&base[row * 64 + (((chunk ^ (row & 7)) << 3))];
}

// ---------------------------------------------------------------------------
// prep: (a) 3 weight transposes f32->bf16  (b) q f32->bf16  (c) K->Kb bf16,
// V->VT bf16 * gamma^{-ml}, per-chunk G^T (bf16) for the state recurrence.
// Flattened grid: [0,3072) transp | [3072,7168) q cvt | [7168,8192) kv+G.
// ---------------------------------------------------------------------------
__global__ __launch_bounds__(256)
void prep(const float* __restrict__ W0, const float* __restrict__ W1,
          const float* __restrict__ W2, ushort_t* __restrict__ T0,
          ushort_t* __restrict__ T1, ushort_t* __restrict__ T2,
          const float* __restrict__ q, ushort_t* __restrict__ q_bf,
          const float* __restrict__ K, const float* __restrict__ V,
          const float* __restrict__ gammas, ushort_t* __restrict__ Kb,
          ushort_t* __restrict__ VT, ushort_t* __restrict__ Gg) {
    __shared__ ushort_t sh[9216];   // 18 KB, reused per branch
    const int bi = blockIdx.x;
    const int tid = threadIdx.x;

    if (bi < 3072) {                // ---- weight transpose+convert
        float* T = (float*)sh;      // [32][36]
        const int z = bi >> 10, rem = bi & 1023;
        const int kt = rem & 31, nt = rem >> 5;
        const float*  W  = (z == 0) ? W0 : (z == 1) ? W1 : W2;
        ushort_t*     WT = (z == 0) ? T0 : (z == 1) ? T1 : T2;
        const int rr = tid >> 3, cc = (tid & 7) * 4;
        float4 w4 = *(const float4*)(W + (size_t)(kt * 32 + rr) * D_ + nt * 32 + cc);
        T[rr * 36 + cc + 0] = w4.x; T[rr * 36 + cc + 1] = w4.y;
        T[rr * 36 + cc + 2] = w4.z; T[rr * 36 + cc + 3] = w4.w;
        __syncthreads();
        ushort_t o[4];
        #pragma unroll
        for (int j = 0; j < 4; ++j) o[j] = f2bf(T[(cc + j) * 36 + rr]);
        *(ushort4*)(WT + (size_t)(nt * 32 + rr) * D_ + kt * 32 + cc) =
            make_ushort4(o[0], o[1], o[2], o[3]);
        return;
    }
    if (bi < 7168) {                // ---- q convert
        const int i = ((bi - 3072) * 256 + tid) * 4;
        float4 x = *(const float4*)(q + i);
        *(ushort4*)(q_bf + i) = make_ushort4(f2bf(x.x), f2bf(x.y), f2bf(x.z), f2bf(x.w));
        return;
    }
    // ---- K/V convert + chunk outer product G^T
    ushort_t* Tv = sh;              // [val][ml] stride 72
    ushort_t* Tk = sh + 4608;       // [kappa][ml] stride 72
    const int rem = bi - 7168;
    const int mt = rem & 31, h = (rem >> 5) & 15, b = rem >> 9;
    const int m0 = mt * 64;
    const int r = tid >> 2, c0 = (tid & 3) * 16;
    const float lg = log2f(gammas[h]);
    const float gm = exp2f(-(float)r * lg);
    {
        const float* src = K + ((size_t)(b * S_ + m0 + r)) * D_ + h * HD_ + c0;
        ushort_t kb[16];
        #pragma unroll
        for (int j4 = 0; j4 < 4; ++j4) {
            float4 x = *(const float4*)(src + j4 * 4);
            kb[j4 * 4 + 0] = f2bf(x.x); kb[j4 * 4 + 1] = f2bf(x.y);
            kb[j4 * 4 + 2] = f2bf(x.z); kb[j4 * 4 + 3] = f2bf(x.w);
        }
        ushort_t* dst = Kb + ((size_t)(b * S_ + m0 + r)) * D_ + h * HD_ + c0;
        *(uint4*)(dst + 0) = *(const uint4*)&kb[0];
        *(uint4*)(dst + 8) = *(const uint4*)&kb[8];
        #pragma unroll
        for (int j = 0; j < 16; ++j) Tk[(c0 + j) * 72 + r] = kb[j];
    }
    {
        const float* src = V + ((size_t)(b * S_ + m0 + r)) * D_ + h * HD_ + c0;
        #pragma unroll
        for (int j4 = 0; j4 < 4; ++j4) {
            float4 x = *(const float4*)(src + j4 * 4);
            Tv[(c0 + j4 * 4 + 0) * 72 + r] = f2bf(x.x * gm);
            Tv[(c0 + j4 * 4 + 1) * 72 + r] = f2bf(x.y * gm);
            Tv[(c0 + j4 * 4 + 2) * 72 + r] = f2bf(x.z * gm);
            Tv[(c0 + j4 * 4 + 3) * 72 + r] = f2bf(x.w * gm);
        }
    }
    __syncthreads();
    {
        ushort_t* dst = VT + ((size_t)((b * H_ + h) * HD_ + r)) * S_ + m0 + c0;
        *(uint4*)(dst + 0) = *(const uint4*)&Tv[r * 72 + c0 + 0];
        *(uint4*)(dst + 8) = *(const uint4*)&Tv[r * 72 + c0 + 8];
    }
    const int w = tid >> 6, lane = tid & 63, quad = lane >> 4, l15 = lane & 15;
    bf16x8 af0 = *(const bf16x8*)&Tv[(w * 16 + l15) * 72 + quad * 8];
    bf16x8 af1 = *(const bf16x8*)&Tv[(w * 16 + l15) * 72 + 32 + quad * 8];
    ushort_t* gout = Gg + ((size_t)((b * H_ + h) * 32 + mt)) * 4096;
    #pragma unroll
    for (int kt2 = 0; kt2 < 4; ++kt2) {
        bf16x8 bf0 = *(const bf16x8*)&Tk[(kt2 * 16 + l15) * 72 + quad * 8];
        bf16x8 bf1 = *(const bf16x8*)&Tk[(kt2 * 16 + l15) * 72 + 32 + quad * 8];
        f32x4 g = {};
        g = __builtin_amdgcn_mfma_f32_16x16x32_bf16(af0, bf0, g, 0, 0, 0);
        g = __builtin_amdgcn_mfma_f32_16x16x32_bf16(af1, bf1, g, 0, 0, 0);
        #pragma unroll
        for (int reg = 0; reg < 4; ++reg)
            gout[(w * 16 + quad * 4 + reg) * 64 + kt2 * 16 + l15] = f2bf(g[reg]);
    }
}

// ---------------------------------------------------------------------------
// Fused dual GEMM + chunk-scan epilogue, double-buffered DMA staging
// (R9 structure — direct-global fragments regressed in R10, reverted).
// PH[m*D+d] = pack(Pp bf16 | Hloc bf16).
// ---------------------------------------------------------------------------
__global__ __launch_bounds__(256)
void gemm_dual_scan(const ushort_t* __restrict__ A, const ushort_t* __restrict__ BTi,
                    const ushort_t* __restrict__ BTg, const float* __restrict__ bi,
                    const float* __restrict__ bg, uint_t* __restrict__ PH,
                    float* __restrict__ cA, float* __restrict__ cU) {
    __shared__ ushort_t smem[32768];   // 64 KB = 2 x (As 8192 | Bi 4096 | Bg 4096)
    const int tid = threadIdx.x;
    const int n0 = blockIdx.x * 64, m0 = blockIdx.y * 128;
    const int w = tid >> 6, lane = tid & 63, quad = lane >> 4, l15 = lane & 15;
    const int wr = (w >> 1) * 64, wc = (w & 1) * 32;
    const int l8 = lane & 7, lr8 = lane >> 3;

    f32x4 acc_i[4][2] = {};
    f32x4 acc_g[4][2] = {};

    auto stage = [&](int k0, int bufo) {
        #pragma unroll
        for (int t = 0; t < 4; ++t) {
            const int row = w * 32 + t * 8 + lr8;
            const int gc = ((l8 ^ (row & 7)) << 3);
            dma16(A + (size_t)(m0 + row) * D_ + k0 + gc, &smem[bufo + row * 64 + l8 * 8]);
        }
        #pragma unroll
        for (int t = 0; t < 2; ++t) {
            const int row = w * 16 + t * 8 + lr8;
            const int gc = ((l8 ^ (row & 7)) << 3);
            dma16(BTi + (size_t)(n0 + row) * D_ + k0 + gc, &smem[bufo + 8192 + row * 64 + l8 * 8]);
            dma16(BTg + (size_t)(n0 + row) * D_ + k0 + gc, &smem[bufo + 12288 + row * 64 + l8 * 8]);
        }
    };

    stage(0, 0);
    __syncthreads();
    for (int t = 0; t < 16; ++t) {
        const int bufo = (t & 1) * 16384;
        if (t < 15) stage((t + 1) * 64, 16384 - bufo);
        const ushort_t* As = smem + bufo;
        const ushort_t* Bi = smem + bufo + 8192;
        const ushort_t* Bg = smem + bufo + 12288;
        #pragma unroll
        for (int kk = 0; kk < 2; ++kk) {
            bf16x8 af[4], bfi[2], bfg[2];
            #pragma unroll
            for (int i = 0; i < 4; ++i)
                af[i] = fragr(As, wr + 16 * i + l15, kk * 4 + quad);
            #pragma unroll
            for (int j = 0; j < 2; ++j) {
                bfi[j] = fragr(Bi, wc + 16 * j + l15, kk * 4 + quad);
                bfg[j] = fragr(Bg, wc + 16 * j + l15, kk * 4 + quad);
            }
            #pragma unroll
            for (int i = 0; i < 4; ++i)
                #pragma unroll
                for (int j = 0; j < 2; ++j) {
                    acc_i[i][j] = __builtin_amdgcn_mfma_f32_16x16x32_bf16(
                        af[i], bfi[j], acc_i[i][j], 0, 0, 0);
                    acc_g[i][j] = __builtin_amdgcn_mfma_f32_16x16x32_bf16(
                        af[i], bfg[j], acc_g[i][j], 0, 0, 0);
                }
        }
        __syncthreads();
    }

    // epilogue in dead staging LDS: Us bf16 [128][64], Gu u16 [128][64]
    ushort_t* Us = smem;
    ushort_t* Gu = smem + 8192;
    #pragma unroll
    for (int j = 0; j < 2; ++j) {
        const int n = wc + 16 * j + l15;
        const float bbi = bi[n0 + n], bbg = bg[n0 + n];
        #pragma unroll
        for (int i = 0; i < 4; ++i) {
            #pragma unroll
            for (int r = 0; r < 4; ++r) {
                const int m = wr + 16 * i + quad * 4 + r;
                Us[m * 64 + n] = f2bf(acc_i[i][j][r] + bbi);
                float g = 1.0f / (1.0f + __expf(-(acc_g[i][j][r] + bbg)));
                Gu[m * 64 + n] = (ushort_t)__float2uint_rn(g * 65535.0f);
            }
        }
    }
    __syncthreads();

    const int nl = tid & 63, c = tid >> 6;
    const int gmb = m0 + c * 32;
    const size_t gbase = (size_t)gmb * D_ + n0 + nl;
    float Aa = 1.0f, hh = 0.0f;
    #pragma unroll 4
    for (int j = 0; j < 32; ++j) {
        const float g = (float)Gu[(c * 32 + j) * 64 + nl] * (1.0f / 65535.0f);
        const float u = bf2f(Us[(c * 32 + j) * 64 + nl]);
        Aa *= g;
        hh = fmaf(g, hh, u);
        PH[gbase + (size_t)j * D_] = pkt(Aa, hh);
    }
    const int bb = gmb >> 11;
    const int ch = (gmb & 2047) >> 5;
    const int ci = ((bb * 64 + ch) << 10) + n0 + nl;
    cA[ci] = Aa;
    cU[ci] = hh;
}

// ---------------------------------------------------------------------------
// Merged mid-kernels: blocks [0,128) = state scan (S_c = g64*(S_{c-1}+G));
// blocks [128,136) = chunk-level gated scan producing carry-ins.
// ---------------------------------------------------------------------------
__global__ __launch_bounds__(256)
void mid_scan(const ushort_t* __restrict__ Gg, const float* __restrict__ gammas,
              ushort_t* __restrict__ Sb, const float* __restrict__ cA,
              const float* __restrict__ cU, float* __restrict__ cIn) {
    const int bi = blockIdx.x;
    if (bi < 128) {
        const int sl = bi & 3, h = (bi >> 2) & 15, b = bi >> 6;
        const float g64 = exp2f(64.0f * log2f(gammas[h]));
        const int r = threadIdx.x >> 4;
        const int cb = (threadIdx.x & 15) * 4;
        const size_t base = ((size_t)((b * H_ + h) * 32)) * 4096 + (sl * 16 + r) * 64 + cb;
        float4 S = make_float4(0.f, 0.f, 0.f, 0.f);
        for (int c = 0; c < 32; ++c) {
            ushort4 g4 = *(const ushort4*)(Gg + base + (size_t)c * 4096);
            ushort4 sb;
            sb.x = f2bf(S.x); sb.y = f2bf(S.y); sb.z = f2bf(S.z); sb.w = f2bf(S.w);
            *(ushort4*)(Sb + base + (size_t)c * 4096) = sb;
            S.x = g64 * (S.x + bf2f(g4.x)); S.y = g64 * (S.y + bf2f(g4.y));
            S.z = g64 * (S.z + bf2f(g4.z)); S.w = g64 * (S.w + bf2f(g4.w));
        }
        return;
    }
    const int t = (bi - 128) * 256 + threadIdx.x;   // 0..2047
    const int d = t & 1023, b = t >> 10;
    float h = 0.0f;
    for (int c0 = 0; c0 < 64; c0 += 16) {
        float Av[16], Uv[16];
        #pragma unroll
        for (int j = 0; j < 16; ++j) {
            const int idx = ((b * 64 + c0 + j) << 10) + d;
            Av[j] = cA[idx]; Uv[j] = cU[idx];
        }
        #pragma unroll
        for (int j = 0; j < 16; ++j) {
            cIn[((b * 64 + c0 + j) << 10) + d] = h;
            h = fmaf(Av[j], h, Uv[j]);
        }
    }
}

// ---------------------------------------------------------------------------
// Retention with fused W_out GEMM AND fused scan-fix. The GEMM A-operand
// h = Hloc + cIn*Pp is computed on the fly from PH during VGPR A-staging
// (deletes the scan_fix kernel + h_bf buffer). WTo staged via dbuf DMA.
// K/V/S DMAs issued up front drain under the GEMM. Then chunkwise retention:
// out^T = S^T.q + VT.(masked QK^T), epilogue scale gamma^{nl}. LDS 56 KB.
// ---------------------------------------------------------------------------
__global__ __launch_bounds__(256)
void retention_fused(const uint_t* __restrict__ PH, const float* __restrict__ cIn,
                     const ushort_t* __restrict__ WTo, const float* __restrict__ bo,
                     const ushort_t* __restrict__ Kb, const ushort_t* __restrict__ VT,
                     const ushort_t* __restrict__ Sb, const float* __restrict__ gammas,
                     float* __restrict__ Out) {
    __shared__ ushort_t smem[28672];   // 56 KB (ushort units)
    // buf0: A[0,4096) B[4096,8192); buf1: A[8192,12288) B[12288,16384)
    // Ks 16384, Vt 20480, Ss 24576; Qs->0, Ps->4096 after the GEMM
    const int tid = threadIdx.x;
    const int nt = blockIdx.x, h = blockIdx.y, b = blockIdx.z;
    const int n0 = nt * 64;
    const float lg = log2f(gammas[h]);
    const int w = tid >> 6, lane = tid & 63, quad = lane >> 4, l15 = lane & 15;
    const int l8 = lane & 7, lr8 = lane >> 3;
    const int nl = w * 16 + l15;
    const size_t bS = (size_t)b * S_;
    const size_t vrow0 = (size_t)((b * H_ + h) * HD_);
    const size_t sbase = ((size_t)((b * H_ + h) * 32 + nt)) * 4096;

    // K/V/S DMAs: complete during the GEMM below (latency hidden)
    #pragma unroll
    for (int t = 0; t < 2; ++t) {
        const int row = w * 16 + t * 8 + lr8;
        const int gc = ((l8 ^ (row & 7)) << 3);
        dma16(Kb + (bS + n0 + row) * D_ + h * HD_ + gc, &smem[16384 + row * 64 + l8 * 8]);
        dma16(VT + (vrow0 + row) * S_ + n0 + gc,        &smem[20480 + row * 64 + l8 * 8]);
        dma16(Sb + sbase + (size_t)row * 64 + gc,       &smem[24576 + row * 64 + l8 * 8]);
    }

    // A-staging indices: thread owns row r, two 8-col chunks cb, cb+1
    const int r = tid >> 2, cb = (tid & 3) * 2;
    const int ch = ((n0 + r) & 2047) >> 5;
    const size_t phrow = (bS + n0 + r) * D_;
    const float* cip = cIn + (((size_t)b * 64 + ch) << 10);

    auto stageA = [&](int k0, int bufo) {
        ushort_t* Ab = smem + bufo;
        #pragma unroll
        for (int cc = 0; cc < 2; ++cc) {
            const int c = cb + cc;
            uint4 pa = *(const uint4*)(PH + phrow + k0 + c * 8);
            uint4 pb = *(const uint4*)(PH + phrow + k0 + c * 8 + 4);
            float4 ca = *(const float4*)(cip + k0 + c * 8);
            float4 cb4 = *(const float4*)(cip + k0 + c * 8 + 4);
            float h0 = fmaf(ca.x,  bf2f((ushort_t)(pa.x & 0xFFFF)), bf2f((ushort_t)(pa.x >> 16)));
            float h1 = fmaf(ca.y,  bf2f((ushort_t)(pa.y & 0xFFFF)), bf2f((ushort_t)(pa.y >> 16)));
            float h2 = fmaf(ca.z,  bf2f((ushort_t)(pa.z & 0xFFFF)), bf2f((ushort_t)(pa.z >> 16)));
            float h3 = fmaf(ca.w,  bf2f((ushort_t)(pa.w & 0xFFFF)), bf2f((ushort_t)(pa.w >> 16)));
            float h4 = fmaf(cb4.x, bf2f((ushort_t)(pb.x & 0xFFFF)), bf2f((ushort_t)(pb.x >> 16)));
            float h5 = fmaf(cb4.y, bf2f((ushort_t)(pb.y & 0xFFFF)), bf2f((ushort_t)(pb.y >> 16)));
            float h6 = fmaf(cb4.z, bf2f((ushort_t)(pb.z & 0xFFFF)), bf2f((ushort_t)(pb.z >> 16)));
            float h7 = fmaf(cb4.w, bf2f((ushort_t)(pb.w & 0xFFFF)), bf2f((ushort_t)(pb.w >> 16)));
            uint4 hw;
            hw.x = pkt(h0, h1); hw.y = pkt(h2, h3);
            hw.z = pkt(h4, h5); hw.w = pkt(h6, h7);
            *(uint4*)&smem[bufo + r * 64 + ((c ^ (r & 7)) << 3)] = hw;
        }
        (void)Ab;
    };
    auto stageB = [&](int k0, int bufo) {
        #pragma unroll
        for (int t = 0; t < 2; ++t) {
            const int row = w * 8 + t * 32 + lr8;
            const int gc = ((l8 ^ (row & 7)) << 3);
            dma16(WTo + ((size_t)(h * 64 + row)) * D_ + k0 + gc,
                  &smem[bufo + 4096 + row * 64 + l8 * 8]);
        }
    };

    stageB(0, 0);
    stageA(0, 0);
    __syncthreads();

    f32x4 acc[4] = {};
    for (int t = 0; t < 16; ++t) {
        const int bufo = (t & 1) * 8192;
        if (t < 15) {
            stageB((t + 1) * 64, 8192 - bufo);   // async DMA
            stageA((t + 1) * 64, 8192 - bufo);   // VGPR-staged h (fused scan-fix)
        }
        const ushort_t* As = smem + bufo;
        const ushort_t* Bs = smem + bufo + 4096;
        #pragma unroll
        for (int kk = 0; kk < 2; ++kk) {
            bf16x8 af = fragr(As, w * 16 + l15, kk * 4 + quad);
            #pragma unroll
            for (int ct = 0; ct < 4; ++ct) {
                bf16x8 bf = fragr(Bs, ct * 16 + l15, kk * 4 + quad);
                acc[ct] = __builtin_amdgcn_mfma_f32_16x16x32_bf16(af, bf, acc[ct], 0, 0, 0);
            }
        }
        __syncthreads();
    }

    // qp tile -> Qs (swizzled bf16) in dead staging region [0,4096)
    ushort_t* Qs = smem;
    ushort_t* Ps = smem + 4096;
    #pragma unroll
    for (int ct = 0; ct < 4; ++ct) {
        const int n = ct * 16 + l15;
        const float bb = bo[h * 64 + n];
        #pragma unroll
        for (int rr = 0; rr < 4; ++rr) {
            const int m = w * 16 + quad * 4 + rr;
            Qs[m * 64 + (((n >> 3) ^ (m & 7)) << 3) + (n & 7)] =
                f2bf((acc[ct][rr] + bb) * 0.125f);
        }
    }
    __syncthreads();

    bf16x8 qf0 = fragr(Qs, nl, quad);
    bf16x8 qf1 = fragr(Qs, nl, 4 + quad);
    const ushort_t* Ks = smem + 16384;
    const ushort_t* Vt = smem + 20480;
    const ushort_t* Ss = smem + 24576;

    f32x4 o[4] = {};
    // cross-chunk: o += S^T-rows x Q
    #pragma unroll
    for (int ct = 0; ct < 4; ++ct) {
        bf16x8 sf0 = fragr(Ss, ct * 16 + l15, quad);
        bf16x8 sf1 = fragr(Ss, ct * 16 + l15, 4 + quad);
        o[ct] = __builtin_amdgcn_mfma_f32_16x16x32_bf16(sf0, qf0, o[ct], 0, 0, 0);
        o[ct] = __builtin_amdgcn_mfma_f32_16x16x32_bf16(sf1, qf1, o[ct], 0, 0, 0);
    }
    // intra-chunk scores^T, causal mask, pack -> Ps
    #pragma unroll
    for (int mt2 = 0; mt2 < 4; ++mt2) {
        bf16x8 kf0 = fragr(Ks, mt2 * 16 + l15, quad);
        bf16x8 kf1 = fragr(Ks, mt2 * 16 + l15, 4 + quad);
        f32x4 s = {};
        s = __builtin_amdgcn_mfma_f32_16x16x32_bf16(kf0, qf0, s, 0, 0, 0);
        s = __builtin_amdgcn_mfma_f32_16x16x32_bf16(kf1, qf1, s, 0, 0, 0);
        const int mbase = mt2 * 16 + quad * 4;
        #pragma unroll
        for (int rr = 0; rr < 4; ++rr)
            if (nl < mbase + rr) s[rr] = 0.0f;
        uint2 pw; pw.x = pkt(s[0], s[1]); pw.y = pkt(s[2], s[3]);
        const int chunk = mbase >> 3;
        *(uint2*)&Ps[nl * 64 + ((chunk ^ (nl & 7)) << 3) + (mbase & 7)] = pw;
    }
    // PV: o += Vt-rows x Ps-row-nl  (Ps rows wave-private)
    bf16x8 pf0 = fragr(Ps, nl, quad);
    bf16x8 pf1 = fragr(Ps, nl, 4 + quad);
    #pragma unroll
    for (int ct = 0; ct < 4; ++ct) {
        bf16x8 vf0 = fragr(Vt, ct * 16 + l15, quad);
        bf16x8 vf1 = fragr(Vt, ct * 16 + l15, 4 + quad);
        o[ct] = __builtin_amdgcn_mfma_f32_16x16x32_bf16(vf0, pf0, o[ct], 0, 0, 0);
        o[ct] = __builtin_amdgcn_mfma_f32_16x16x32_bf16(vf1, pf1, o[ct], 0, 0, 0);
    }

    const float esc = exp2f((float)nl * lg);
    const size_t ob = (bS + n0 + nl) * D_ + h * HD_;
    #pragma unroll
    for (int ct = 0; ct < 4; ++ct) {
        f32x4 t = o[ct] * esc;
        *(f32x4*)(Out + ob + ct * 16 + quad * 4) = t;
    }
}

// ---------------------------------------------------------------------------
extern "C" void kernel_launch(void* const* d_in, const int* in_sizes, int n_in,
                              void* d_out, int out_size, void* d_ws, size_t ws_size,
                              hipStream_t stream) {
    const float* q      = (const float*)d_in[0];
    const float* k      = (const float*)d_in[1];
    const float* v      = (const float*)d_in[2];
    const float* W_in   = (const float*)d_in[3];
    const float* b_in   = (const float*)d_in[4];
    const float* W_gate = (const float*)d_in[5];
    const float* b_gate = (const float*)d_in[6];
    const float* W_out  = (const float*)d_in[7];
    const float* b_out  = (const float*)d_in[8];
    const float* gammas = (const float*)d_in[9];
    float* out = (float*)d_out;

    char* ws = (char*)d_ws;
    const size_t MB = 1024 * 1024;
    ushort_t* q_bf    = (ushort_t*)(ws);              // [0,8)
    ushort_t* k_bf    = (ushort_t*)(ws + 8 * MB);     // [8,16)
    ushort_t* VT      = (ushort_t*)(ws + 16 * MB);    // [16,24)
    ushort_t* WT_in   = (ushort_t*)(ws + 24 * MB);    // [24,26)
    ushort_t* WT_gate = (ushort_t*)(ws + 26 * MB);    // [26,28)
    ushort_t* WT_out  = (ushort_t*)(ws + 28 * MB);    // [28,30)
    ushort_t* Sb      = (ushort_t*)(ws + 30 * MB);    // [30,38)
    ushort_t* Gg      = (ushort_t*)(ws + 38 * MB);    // [38,46)
    uint_t*   PH      = (uint_t*)(ws + 48 * MB);      // [48,64)
    float*    cA      = (float*)(ws + 72 * MB);
    float*    cU      = (float*)(ws + 72 * MB + 512 * 1024);
    float*    cIn     = (float*)(ws + 73 * MB);

    prep<<<8192, 256, 0, stream>>>(W_in, W_gate, W_out, WT_in, WT_gate, WT_out,
                                   q, q_bf, k, v, gammas, k_bf, VT, Gg);

    gemm_dual_scan<<<dim3(D_ / 64, M_ / 128), 256, 0, stream>>>(
        q_bf, WT_in, WT_gate, b_in, b_gate, PH, cA, cU);

    mid_scan<<<136, 256, 0, stream>>>(Gg, gammas, Sb, cA, cU, cIn);

    retention_fused<<<dim3(S_ / 64, H_, B_), 256, 0, stream>>>(
        PH, cIn, WT_out, b_out, k_bf, VT, Sb, gammas, out);
}

// Round 12
// 185.062 us; speedup vs baseline: 1.4993x; 1.0899x over previous
//
#include <hip/hip_runtime.h>
#include <math.h>

#define B_  2
#define S_  2048
#define D_  1024
#define H_  16
#define HD_ 64
#define M_  (B_*S_)

typedef unsigned short ushort_t;
typedef unsigned int   uint_t;
typedef __attribute__((ext_vector_type(8))) short bf16x8;
typedef __attribute__((ext_vector_type(4))) float f32x4;

__device__ __forceinline__ ushort_t f2bf(float f) {
    uint_t u = __builtin_bit_cast(uint_t, f);
    u += 0x7FFFu + ((u >> 16) & 1u);           // RNE
    return (ushort_t)(u >> 16);
}
__device__ __forceinline__ float bf2f(ushort_t h) {
    uint_t u = (uint_t)h << 16;
    return __builtin_bit_cast(float, u);
}
// truncating pack: two f32 -> (bf16(lo) | bf16(hi)<<16), one v_perm_b32
__device__ __forceinline__ uint_t pkt(float lo, float hi) {
    return __builtin_amdgcn_perm(__builtin_bit_cast(uint_t, hi),
                                 __builtin_bit_cast(uint_t, lo), 0x07060302u);
}
// async global->LDS, 16B per lane; lds addr = wave-uniform base + lane*16
__device__ __forceinline__ void dma16(const ushort_t* g, ushort_t* l) {
    __builtin_amdgcn_global_load_lds(
        (const __attribute__((address_space(1))) uint_t*)g,
        (__attribute__((address_space(3))) uint_t*)l, 16, 0, 0);
}
// swizzled fragment read from unpadded [row][64] bf16 tile
__device__ __forceinline__ bf16x8 fragr(const ushort_t* base, int row, int chunk) {
    return *(const bf16x8*)&base[row * 64 + (((chunk ^ (row & 7)) << 3))];
}

// ---------------------------------------------------------------------------
// Transpose + convert all three weights: W [K][N] f32 -> WT [N][K] bf16
// ---------------------------------------------------------------------------
__global__ __launch_bounds__(256)
void transp_cvt3(const float* __restrict__ W0, const float* __restrict__ W1,
                 const float* __restrict__ W2, ushort_t* __restrict__ T0,
                 ushort_t* __restrict__ T1, ushort_t* __restrict__ T2) {
    __shared__ float T[32][36];
    const float*  W  = (blockIdx.z == 0) ? W0 : (blockIdx.z == 1) ? W1 : W2;
    ushort_t*     WT = (blockIdx.z == 0) ? T0 : (blockIdx.z == 1) ? T1 : T2;
    const int kt = blockIdx.x, nt = blockIdx.y;
    const int t = threadIdx.x;
    const int rr = t >> 3, cc = (t & 7) * 4;
    float4 w4 = *(const float4*)(W + (size_t)(kt * 32 + rr) * D_ + nt * 32 + cc);
    T[rr][cc + 0] = w4.x; T[rr][cc + 1] = w4.y; T[rr][cc + 2] = w4.z; T[rr][cc + 3] = w4.w;
    __syncthreads();
    ushort_t o[4];
    #pragma unroll
    for (int j = 0; j < 4; ++j) o[j] = f2bf(T[cc + j][rr]);
    *(ushort4*)(WT + (size_t)(nt * 32 + rr) * D_ + kt * 32 + cc) =
        make_ushort4(o[0], o[1], o[2], o[3]);
}

__global__ __launch_bounds__(256)
void cvt_bf16(const float* __restrict__ X, ushort_t* __restrict__ Y) {
    const int i = (blockIdx.x * 256 + threadIdx.x) * 4;
    float4 x = *(const float4*)(X + i);
    *(ushort4*)(Y + i) = make_ushort4(f2bf(x.x), f2bf(x.y), f2bf(x.z), f2bf(x.w));
}

// ---------------------------------------------------------------------------
// K -> Kb bf16 (straight); V -> VT [B,H,HD,S] bf16 * gamma^{-ml};
// plus per-chunk outer product G^T[val][kappa] (f32) for the state recurrence.
// ---------------------------------------------------------------------------
__global__ __launch_bounds__(256)
void kv_cvt_g(const float* __restrict__ K, const float* __restrict__ V,
              const float* __restrict__ gammas, ushort_t* __restrict__ Kb,
              ushort_t* __restrict__ VT, float* __restrict__ Gg) {
    __shared__ ushort_t Tv[64 * 72];   // [val][ml]
    __shared__ ushort_t Tk[64 * 72];   // [kappa][ml]
    const int mt = blockIdx.x, h = blockIdx.y, b = blockIdx.z;
    const int m0 = mt * 64;
    const int tid = threadIdx.x;
    const int r = tid >> 2, c0 = (tid & 3) * 16;
    const float lg = log2f(gammas[h]);
    const float gm = exp2f(-(float)r * lg);   // gamma^{-ml}, ml = r
    {
        const float* src = K + ((size_t)(b * S_ + m0 + r)) * D_ + h * HD_ + c0;
        ushort_t kb[16];
        #pragma unroll
        for (int j4 = 0; j4 < 4; ++j4) {
            float4 x = *(const float4*)(src + j4 * 4);
            kb[j4 * 4 + 0] = f2bf(x.x); kb[j4 * 4 + 1] = f2bf(x.y);
            kb[j4 * 4 + 2] = f2bf(x.z); kb[j4 * 4 + 3] = f2bf(x.w);
        }
        ushort_t* dst = Kb + ((size_t)(b * S_ + m0 + r)) * D_ + h * HD_ + c0;
        *(uint4*)(dst + 0) = *(const uint4*)&kb[0];
        *(uint4*)(dst + 8) = *(const uint4*)&kb[8];
        #pragma unroll
        for (int j = 0; j < 16; ++j) Tk[(c0 + j) * 72 + r] = kb[j];
    }
    {
        const float* src = V + ((size_t)(b * S_ + m0 + r)) * D_ + h * HD_ + c0;
        #pragma unroll
        for (int j4 = 0; j4 < 4; ++j4) {
            float4 x = *(const float4*)(src + j4 * 4);
            Tv[(c0 + j4 * 4 + 0) * 72 + r] = f2bf(x.x * gm);
            Tv[(c0 + j4 * 4 + 1) * 72 + r] = f2bf(x.y * gm);
            Tv[(c0 + j4 * 4 + 2) * 72 + r] = f2bf(x.z * gm);
            Tv[(c0 + j4 * 4 + 3) * 72 + r] = f2bf(x.w * gm);
        }
    }
    __syncthreads();
    {
        ushort_t* dst = VT + ((size_t)((b * H_ + h) * HD_ + r)) * S_ + m0 + c0;
        *(uint4*)(dst + 0) = *(const uint4*)&Tv[r * 72 + c0 + 0];
        *(uint4*)(dst + 8) = *(const uint4*)&Tv[r * 72 + c0 + 8];
    }
    // G^T = Tv . Tk^T via MFMA
    const int w = tid >> 6, lane = tid & 63, quad = lane >> 4, l15 = lane & 15;
    bf16x8 af0 = *(const bf16x8*)&Tv[(w * 16 + l15) * 72 + quad * 8];
    bf16x8 af1 = *(const bf16x8*)&Tv[(w * 16 + l15) * 72 + 32 + quad * 8];
    float* gout = Gg + ((size_t)((b * H_ + h) * 32 + mt)) * 4096;
    #pragma unroll
    for (int kt2 = 0; kt2 < 4; ++kt2) {
        bf16x8 bf0 = *(const bf16x8*)&Tk[(kt2 * 16 + l15) * 72 + quad * 8];
        bf16x8 bf1 = *(const bf16x8*)&Tk[(kt2 * 16 + l15) * 72 + 32 + quad * 8];
        f32x4 g = {};
        g = __builtin_amdgcn_mfma_f32_16x16x32_bf16(af0, bf0, g, 0, 0, 0);
        g = __builtin_amdgcn_mfma_f32_16x16x32_bf16(af1, bf1, g, 0, 0, 0);
        #pragma unroll
        for (int reg = 0; reg < 4; ++reg)
            gout[(w * 16 + quad * 4 + reg) * 64 + kt2 * 16 + l15] = g[reg];
    }
}

// ---------------------------------------------------------------------------
// Fused dual GEMM + chunk-scan epilogue, double-buffered DMA staging.
// ---------------------------------------------------------------------------
__global__ __launch_bounds__(256)
void gemm_dual_scan(const ushort_t* __restrict__ A, const ushort_t* __restrict__ BTi,
                    const ushort_t* __restrict__ BTg, const float* __restrict__ bi,
                    const float* __restrict__ bg, float* __restrict__ Hloc,
                    ushort_t* __restrict__ Pp, float* __restrict__ cA,
                    float* __restrict__ cU) {
    __shared__ ushort_t smem[32768];   // 64 KB = 2 x (As 8192 | Bi 4096 | Bg 4096)
    const int tid = threadIdx.x;
    const int n0 = blockIdx.x * 64, m0 = blockIdx.y * 128;
    const int w = tid >> 6, lane = tid & 63, quad = lane >> 4, l15 = lane & 15;
    const int wr = (w >> 1) * 64, wc = (w & 1) * 32;
    const int l8 = lane & 7, lr8 = lane >> 3;

    f32x4 acc_i[4][2] = {};
    f32x4 acc_g[4][2] = {};

    auto stage = [&](int k0, int bufo) {
        #pragma unroll
        for (int t = 0; t < 4; ++t) {
            const int row = w * 32 + t * 8 + lr8;
            const int gc = ((l8 ^ (row & 7)) << 3);
            dma16(A + (size_t)(m0 + row) * D_ + k0 + gc, &smem[bufo + row * 64 + l8 * 8]);
        }
        #pragma unroll
        for (int t = 0; t < 2; ++t) {
            const int row = w * 16 + t * 8 + lr8;
            const int gc = ((l8 ^ (row & 7)) << 3);
            dma16(BTi + (size_t)(n0 + row) * D_ + k0 + gc, &smem[bufo + 8192 + row * 64 + l8 * 8]);
            dma16(BTg + (size_t)(n0 + row) * D_ + k0 + gc, &smem[bufo + 12288 + row * 64 + l8 * 8]);
        }
    };

    stage(0, 0);
    __syncthreads();
    for (int t = 0; t < 16; ++t) {
        const int bufo = (t & 1) * 16384;
        if (t < 15) stage((t + 1) * 64, 16384 - bufo);
        const ushort_t* As = smem + bufo;
        const ushort_t* Bi = smem + bufo + 8192;
        const ushort_t* Bg = smem + bufo + 12288;
        #pragma unroll
        for (int kk = 0; kk < 2; ++kk) {
            bf16x8 af[4], bfi[2], bfg[2];
            #pragma unroll
            for (int i = 0; i < 4; ++i)
                af[i] = fragr(As, wr + 16 * i + l15, kk * 4 + quad);
            #pragma unroll
            for (int j = 0; j < 2; ++j) {
                bfi[j] = fragr(Bi, wc + 16 * j + l15, kk * 4 + quad);
                bfg[j] = fragr(Bg, wc + 16 * j + l15, kk * 4 + quad);
            }
            #pragma unroll
            for (int i = 0; i < 4; ++i)
                #pragma unroll
                for (int j = 0; j < 2; ++j) {
                    acc_i[i][j] = __builtin_amdgcn_mfma_f32_16x16x32_bf16(
                        af[i], bfi[j], acc_i[i][j], 0, 0, 0);
                    acc_g[i][j] = __builtin_amdgcn_mfma_f32_16x16x32_bf16(
                        af[i], bfg[j], acc_g[i][j], 0, 0, 0);
                }
        }
        __syncthreads();
    }

    // epilogue: reuse staging LDS. Us bf16, Gu u16 fixed-point gate.
    ushort_t* Us = smem;
    ushort_t* Gu = smem + 8448;
    #pragma unroll
    for (int j = 0; j < 2; ++j) {
        const int n = wc + 16 * j + l15;
        const float bbi = bi[n0 + n], bbg = bg[n0 + n];
        #pragma unroll
        for (int i = 0; i < 4; ++i) {
            #pragma unroll
            for (int r = 0; r < 4; ++r) {
                const int m = wr + 16 * i + quad * 4 + r;
                Us[m * 66 + n] = f2bf(acc_i[i][j][r] + bbi);
                float g = 1.0f / (1.0f + __expf(-(acc_g[i][j][r] + bbg)));
                Gu[m * 66 + n] = (ushort_t)__float2uint_rn(g * 65535.0f);
            }
        }
    }
    __syncthreads();

    const int nl = tid & 63, c = tid >> 6;
    const int gmb = m0 + c * 32;
    const size_t gbase = (size_t)gmb * D_ + n0 + nl;
    float Aa = 1.0f, hh = 0.0f;
    #pragma unroll 4
    for (int j = 0; j < 32; ++j) {
        const float g = (float)Gu[(c * 32 + j) * 66 + nl] * (1.0f / 65535.0f);
        const float u = bf2f(Us[(c * 32 + j) * 66 + nl]);
        Aa *= g;
        hh = fmaf(g, hh, u);
        Pp[gbase + (size_t)j * D_] = f2bf(Aa);
        Hloc[gbase + (size_t)j * D_] = hh;
    }
    const int bb = gmb >> 11;
    const int ch = (gmb & 2047) >> 5;
    const int ci = ((bb * 64 + ch) << 10) + n0 + nl;
    cA[ci] = Aa;
    cU[ci] = hh;
}

// ---------------------------------------------------------------------------
// Merged mid-kernels: blocks [0,128) = state scan (S_c = g64*(S_{c-1}+G), f32
// G input, bf16 S out); blocks [128,136) = chunk-level gated scan -> carry-ins.
// ---------------------------------------------------------------------------
__global__ __launch_bounds__(256)
void mid_scan(const float* __restrict__ Gg, const float* __restrict__ gammas,
              ushort_t* __restrict__ Sb, const float* __restrict__ cA,
              const float* __restrict__ cU, float* __restrict__ cIn) {
    const int bi = blockIdx.x;
    if (bi < 128) {
        const int sl = bi & 3, h = (bi >> 2) & 15, b = bi >> 6;
        const float g64 = exp2f(64.0f * log2f(gammas[h]));
        const int r = threadIdx.x >> 4;
        const int cb = (threadIdx.x & 15) * 4;
        const size_t base = ((size_t)((b * H_ + h) * 32)) * 4096 + (sl * 16 + r) * 64 + cb;
        float4 S = make_float4(0.f, 0.f, 0.f, 0.f);
        for (int c = 0; c < 32; ++c) {
            ushort4 sb;
            sb.x = f2bf(S.x); sb.y = f2bf(S.y); sb.z = f2bf(S.z); sb.w = f2bf(S.w);
            *(ushort4*)(Sb + base + (size_t)c * 4096) = sb;
            float4 G = *(const float4*)(Gg + base + (size_t)c * 4096);
            S.x = g64 * (S.x + G.x); S.y = g64 * (S.y + G.y);
            S.z = g64 * (S.z + G.z); S.w = g64 * (S.w + G.w);
        }
        return;
    }
    const int t = (bi - 128) * 256 + threadIdx.x;   // 0..2047
    const int d = t & 1023, b = t >> 10;
    float h = 0.0f;
    for (int c0 = 0; c0 < 64; c0 += 16) {
        float Av[16], Uv[16];
        #pragma unroll
        for (int j = 0; j < 16; ++j) {
            const int idx = ((b * 64 + c0 + j) << 10) + d;
            Av[j] = cA[idx]; Uv[j] = cU[idx];
        }
        #pragma unroll
        for (int j = 0; j < 16; ++j) {
            cIn[((b * 64 + c0 + j) << 10) + d] = h;
            h = fmaf(Av[j], h, Uv[j]);
        }
    }
}

// ---------------------------------------------------------------------------
// Elementwise fix: h = h_local + cIn[chunk] * P  -> bf16
// ---------------------------------------------------------------------------
__global__ __launch_bounds__(256)
void scan_fix(const float* __restrict__ Hloc, const ushort_t* __restrict__ Pp,
              const float* __restrict__ cIn, ushort_t* __restrict__ hout) {
    const int i = (blockIdx.x * 256 + threadIdx.x) * 4;
    const int m = i >> 10, d = i & 1023;
    const int b = m >> 11, ch = (m & 2047) >> 5;
    float4 hl = *(const float4*)(Hloc + i);
    ushort4 p4 = *(const ushort4*)(Pp + i);
    float4 ci = *(const float4*)(cIn + ((b * 64 + ch) << 10) + d);
    ushort4 o;
    o.x = f2bf(fmaf(ci.x, bf2f(p4.x), hl.x));
    o.y = f2bf(fmaf(ci.y, bf2f(p4.y), hl.y));
    o.z = f2bf(fmaf(ci.z, bf2f(p4.z), hl.z));
    o.w = f2bf(fmaf(ci.w, bf2f(p4.w), hl.w));
    *(ushort4*)(hout + i) = o;
}

// ---------------------------------------------------------------------------
// Single GEMM (W_out), double-buffered DMA: C = (A.WT + bias)*scale -> bf16
// ---------------------------------------------------------------------------
__global__ __launch_bounds__(256)
void gemm_out_a(const ushort_t* __restrict__ A, const ushort_t* __restrict__ BT,
                const float* __restrict__ bias, float scale,
                ushort_t* __restrict__ Cb) {
    __shared__ ushort_t smem[24576];   // 48 KB = 2 x (As 8192 | Bs 4096)
    const int tid = threadIdx.x;
    const int n0 = blockIdx.x * 64, m0 = blockIdx.y * 128;
    const int w = tid >> 6, lane = tid & 63, quad = lane >> 4, l15 = lane & 15;
    const int wr = (w >> 1) * 64, wc = (w & 1) * 32;
    const int l8 = lane & 7, lr8 = lane >> 3;

    f32x4 acc[4][2] = {};

    auto stage = [&](int k0, int bufo) {
        #pragma unroll
        for (int t = 0; t < 4; ++t) {
            const int row = w * 32 + t * 8 + lr8;
            const int gc = ((l8 ^ (row & 7)) << 3);
            dma16(A + (size_t)(m0 + row) * D_ + k0 + gc, &smem[bufo + row * 64 + l8 * 8]);
        }
        #pragma unroll
        for (int t = 0; t < 2; ++t) {
            const int row = w * 16 + t * 8 + lr8;
            const int gc = ((l8 ^ (row & 7)) << 3);
            dma16(BT + (size_t)(n0 + row) * D_ + k0 + gc, &smem[bufo + 8192 + row * 64 + l8 * 8]);
        }
    };

    stage(0, 0);
    __syncthreads();
    for (int t = 0; t < 16; ++t) {
        const int bufo = (t & 1) * 12288;
        if (t < 15) stage((t + 1) * 64, 12288 - bufo);
        const ushort_t* As = smem + bufo;
        const ushort_t* Bs = smem + bufo + 8192;
        #pragma unroll
        for (int kk = 0; kk < 2; ++kk) {
            bf16x8 af[4], bf[2];
            #pragma unroll
            for (int i = 0; i < 4; ++i)
                af[i] = fragr(As, wr + 16 * i + l15, kk * 4 + quad);
            #pragma unroll
            for (int j = 0; j < 2; ++j)
                bf[j] = fragr(Bs, wc + 16 * j + l15, kk * 4 + quad);
            #pragma unroll
            for (int i = 0; i < 4; ++i)
                #pragma unroll
                for (int j = 0; j < 2; ++j)
                    acc[i][j] = __builtin_amdgcn_mfma_f32_16x16x32_bf16(
                        af[i], bf[j], acc[i][j], 0, 0, 0);
        }
        __syncthreads();
    }

    #pragma unroll
    for (int j = 0; j < 2; ++j) {
        const int n = n0 + wc + 16 * j + l15;
        const float bb = bias[n];
        #pragma unroll
        for (int i = 0; i < 4; ++i)
            #pragma unroll
            for (int r = 0; r < 4; ++r) {
                const int m = m0 + wr + 16 * i + quad * 4 + r;
                Cb[(size_t)m * D_ + n] = f2bf((acc[i][j][r] + bb) * scale);
            }
    }
}

// ---------------------------------------------------------------------------
// Retention, chunkwise-recurrent: one 64-row q-tile per block, uniform work.
// out^T[val][nl] = S^T.q + VT.(masked QK^T); epilogue scale gamma^{nl}.
// Qb pre-scaled 1/8; VT pre-scaled gamma^{-ml}; Sb = state entering chunk.
// LDS 40 KB -> 4 blocks/CU.
// ---------------------------------------------------------------------------
__global__ __launch_bounds__(256)
void retention_chunk(const ushort_t* __restrict__ Qb, const ushort_t* __restrict__ Kb,
                     const ushort_t* __restrict__ VT, const ushort_t* __restrict__ Sb,
                     const float* __restrict__ gammas, float* __restrict__ Out) {
    __shared__ ushort_t smem[20480];   // 40 KB
    ushort_t* Qs = smem;               // [nl][64]
    ushort_t* Ks = smem + 4096;        // [ml][64]
    ushort_t* Vt = smem + 8192;        // [val][ml]
    ushort_t* Ss = smem + 12288;       // [val][kappa]
    ushort_t* Ps = smem + 16384;       // [nl][ml] swizzled
    const int tid = threadIdx.x;
    const int nt = blockIdx.x, h = blockIdx.y, b = blockIdx.z;
    const int n0 = nt * 64;
    const float lg = log2f(gammas[h]);
    const int w = tid >> 6, lane = tid & 63, quad = lane >> 4, l15 = lane & 15;
    const int l8 = lane & 7, lr8 = lane >> 3;
    const int nl = w * 16 + l15;
    const size_t bS = (size_t)b * S_;
    const size_t vrow0 = (size_t)((b * H_ + h) * HD_);
    const size_t sbase = ((size_t)((b * H_ + h) * 32 + nt)) * 4096;

    #pragma unroll
    for (int t = 0; t < 2; ++t) {
        const int row = w * 16 + t * 8 + lr8;
        const int gc = ((l8 ^ (row & 7)) << 3);
        dma16(Qb + (bS + n0 + row) * D_ + h * HD_ + gc, &Qs[row * 64 + l8 * 8]);
        dma16(Kb + (bS + n0 + row) * D_ + h * HD_ + gc, &Ks[row * 64 + l8 * 8]);
        dma16(VT + (vrow0 + row) * S_ + n0 + gc, &Vt[row * 64 + l8 * 8]);
        dma16(Sb + sbase + (size_t)row * 64 + gc, &Ss[row * 64 + l8 * 8]);
    }
    __syncthreads();

    bf16x8 qf0 = fragr(Qs, nl, quad);
    bf16x8 qf1 = fragr(Qs, nl, 4 + quad);

    f32x4 o[4] = {};
    // cross-chunk: o[ct] += S^T-rows(A) x Q-rows(B)
    #pragma unroll
    for (int ct = 0; ct < 4; ++ct) {
        bf16x8 sf0 = fragr(Ss, ct * 16 + l15, quad);
        bf16x8 sf1 = fragr(Ss, ct * 16 + l15, 4 + quad);
        o[ct] = __builtin_amdgcn_mfma_f32_16x16x32_bf16(sf0, qf0, o[ct], 0, 0, 0);
        o[ct] = __builtin_amdgcn_mfma_f32_16x16x32_bf16(sf1, qf1, o[ct], 0, 0, 0);
    }
    // intra-chunk scores^T[ml][nl], causal mask, pack -> Ps
    #pragma unroll
    for (int mt2 = 0; mt2 < 4; ++mt2) {
        bf16x8 kf0 = fragr(Ks, mt2 * 16 + l15, quad);
        bf16x8 kf1 = fragr(Ks, mt2 * 16 + l15, 4 + quad);
        f32x4 s = {};
        s = __builtin_amdgcn_mfma_f32_16x16x32_bf16(kf0, qf0, s, 0, 0, 0);
        s = __builtin_amdgcn_mfma_f32_16x16x32_bf16(kf1, qf1, s, 0, 0, 0);
        const int mbase = mt2 * 16 + quad * 4;
        #pragma unroll
        for (int r = 0; r < 4; ++r)
            if (nl < mbase + r) s[r] = 0.0f;
        uint2 pw; pw.x = pkt(s[0], s[1]); pw.y = pkt(s[2], s[3]);
        const int chunk = mbase >> 3;
        *(uint2*)&Ps[nl * 64 + ((chunk ^ (nl & 7)) << 3) + (mbase & 7)] = pw;
    }
    // PV: o[ct] += Vt-rows(A) x Ps-row-nl(B)   (Ps rows wave-private)
    bf16x8 pf0 = fragr(Ps, nl, quad);
    bf16x8 pf1 = fragr(Ps, nl, 4 + quad);
    #pragma unroll
    for (int ct = 0; ct < 4; ++ct) {
        bf16x8 vf0 = fragr(Vt, ct * 16 + l15, quad);
        bf16x8 vf1 = fragr(Vt, ct * 16 + l15, 4 + quad);
        o[ct] = __builtin_amdgcn_mfma_f32_16x16x32_bf16(vf0, pf0, o[ct], 0, 0, 0);
        o[ct] = __builtin_amdgcn_mfma_f32_16x16x32_bf16(vf1, pf1, o[ct], 0, 0, 0);
    }

    const float esc = exp2f((float)nl * lg);
    const size_t ob = (bS + n0 + nl) * D_ + h * HD_;
    #pragma unroll
    for (int ct = 0; ct < 4; ++ct) {
        f32x4 t = o[ct] * esc;
        *(f32x4*)(Out + ob + ct * 16 + quad * 4) = t;
    }
}

// ---------------------------------------------------------------------------
extern "C" void kernel_launch(void* const* d_in, const int* in_sizes, int n_in,
                              void* d_out, int out_size, void* d_ws, size_t ws_size,
                              hipStream_t stream) {
    const float* q      = (const float*)d_in[0];
    const float* k      = (const float*)d_in[1];
    const float* v      = (const float*)d_in[2];
    const float* W_in   = (const float*)d_in[3];
    const float* b_in   = (const float*)d_in[4];
    const float* W_gate = (const float*)d_in[5];
    const float* b_gate = (const float*)d_in[6];
    const float* W_out  = (const float*)d_in[7];
    const float* b_out  = (const float*)d_in[8];
    const float* gammas = (const float*)d_in[9];
    float* out = (float*)d_out;

    char* ws = (char*)d_ws;
    const size_t MB = 1024 * 1024;
    float*    Hloc    = (float*)(ws);                 // [0,16) dead after scan_fix
    ushort_t* Pp      = (ushort_t*)(ws + 16 * MB);    // [16,24) dead after scan_fix
    ushort_t* h_bf    = (ushort_t*)(ws + 24 * MB);    // [24,32)
    ushort_t* q_bf    = (ushort_t*)(ws + 32 * MB);    // [32,40) (reused as qp)
    ushort_t* WT_in   = (ushort_t*)(ws + 40 * MB);
    ushort_t* WT_gate = (ushort_t*)(ws + 42 * MB);
    ushort_t* WT_out  = (ushort_t*)(ws + 44 * MB);
    float*    cA      = (float*)(ws + 46 * MB);
    float*    cU      = (float*)(ws + 46 * MB + 512 * 1024);
    float*    cIn     = (float*)(ws + 47 * MB);
    ushort_t* k_bf    = (ushort_t*)(ws + 48 * MB);    // [48,56)
    ushort_t* VT      = (ushort_t*)(ws + 56 * MB);    // [56,64)
    float*    Gg      = (float*)(ws + 64 * MB);       // [64,80)
    ushort_t* Sb      = (ushort_t*)(ws + 80 * MB);    // [80,88)
    ushort_t* qp_bf   = q_bf;

    transp_cvt3<<<dim3(D_ / 32, D_ / 32, 3), 256, 0, stream>>>(
        W_in, W_gate, W_out, WT_in, WT_gate, WT_out);
    cvt_bf16<<<(M_ * D_) / (256 * 4), 256, 0, stream>>>(q, q_bf);

    gemm_dual_scan<<<dim3(D_ / 64, M_ / 128), 256, 0, stream>>>(
        q_bf, WT_in, WT_gate, b_in, b_gate, Hloc, Pp, cA, cU);

    kv_cvt_g<<<dim3(S_ / 64, H_, B_), 256, 0, stream>>>(k, v, gammas, k_bf, VT, Gg);

    mid_scan<<<136, 256, 0, stream>>>(Gg, gammas, Sb, cA, cU, cIn);
    scan_fix<<<(M_ * D_) / 1024, 256, 0, stream>>>(Hloc, Pp, cIn, h_bf);

    gemm_out_a<<<dim3(D_ / 64, M_ / 128), 256, 0, stream>>>(
        h_bf, WT_out, b_out, 0.125f, qp_bf);

    retention_chunk<<<dim3(S_ / 64, H_, B_), 256, 0, stream>>>(
        qp_bf, k_bf, VT, Sb, gammas, out);
}